// Round 13
// baseline (31.354 us; speedup 1.0000x reference)
//
#include <hip/hip_runtime.h>

// Problem constants (from reference setup_inputs)
#define N_  8
#define K_  32
#define TK_ 128
#define TC_ 256
#define D_  512
#define D4_ (D_ / 4)               // 128 float4 per emb row
#define TOUT_ (TK_ + TC_)          // 384
#define NEGINF_ (-1e20f)
#define INV_SQRT_D_ 0.044194173824159216f   // 1/sqrt(512)

// d_out layout (float): full_enc [N,384,512] | full_mask [N,384] | ck_attn [N,32]
#define OUT_MASK_OFF_ 1572864
#define OUT_ATTN_OFF_ 1575936

#define QPC_ 8                      // ctx slices per row
#define QTOK_ (TC_ / QPC_)          // 32 tokens per slice
#define POOLB_ (N_ * QPC_)          // 64 ctx pool blocks
#define KNOWB_ (N_ * K_)            // 256 (n,k) pairs

// ---------------------------------------------------------------
// Kernel 1 (64 blocks x 1024): ctx pooling + write-through of the
// full_enc context rows (data already in registers). Block 0 zero-inits
// the K2 accumulators (pdot/kcnt/kdone) and the argmax keys.
__global__ __launch_bounds__(1024) void ctx_pool_kernel(
        const int* __restrict__ src_tokens,
        const float* __restrict__ emb,
        float* __restrict__ full_enc,
        float* __restrict__ full_mask,
        float4* __restrict__ partial,        // [64][128] float4
        int* __restrict__ pcnt,              // [64]
        float* __restrict__ pdot,            // [256]
        int* __restrict__ kcnt,              // [256]
        unsigned int* __restrict__ kdone,    // [256]
        unsigned long long* __restrict__ key) {  // [8]
    const int bid = blockIdx.x;
    const int n = bid >> 3, q = bid & 7;
    const int tid = threadIdx.x;
    const int tg = tid >> 7, lane = tid & 127;
    const float4* emb4 = (const float4*)emb;

    __shared__ int s_tok[QTOK_];
    __shared__ float4 s_red[8][D4_];   // 16 KB
    __shared__ int s_cnt[8];

    if (bid == 0) {                     // per-call reset of K2 accumulators
        if (tid < KNOWB_) { pdot[tid] = 0.f; kcnt[tid] = 0; kdone[tid] = 0u; }
        if (tid < N_) key[tid] = 0ull;
    }
    if (tid < QTOK_) s_tok[tid] = src_tokens[n * TC_ + q * QTOK_ + tid];
    __syncthreads();

    float4 acc = make_float4(0.f, 0.f, 0.f, 0.f);
    int cnt = 0;
    #pragma unroll
    for (int i = 0; i < QTOK_ / 8; ++i) {        // 4 tokens per thread
        const int t = tg + i * 8;
        const int tok = s_tok[t];
        const float4 v = emb4[(size_t)tok * D4_ + lane];  // row 0 is valid
        // write-through to full_enc context region (emb[tok] regardless of pad)
        const int row = TK_ + q * QTOK_ + t;
        ((float4*)(full_enc + ((size_t)n * TOUT_ + row) * D_))[lane] = v;
        if (lane == 0) full_mask[n * TOUT_ + row] = (tok != 0) ? 1.0f : 0.0f;

        const bool use = (tok != 0);
        cnt += use ? 1 : 0;
        acc.x += use ? v.x : 0.f;
        acc.y += use ? v.y : 0.f;
        acc.z += use ? v.z : 0.f;
        acc.w += use ? v.w : 0.f;
    }
    s_red[tg][lane] = acc;
    if (lane == 0) s_cnt[tg] = cnt;
    __syncthreads();

    if (tg == 0) {
        float4 tot = s_red[0][lane];
        #pragma unroll
        for (int j = 1; j < 8; ++j) {
            const float4 v = s_red[j][lane];
            tot.x += v.x; tot.y += v.y; tot.z += v.z; tot.w += v.w;
        }
        partial[bid * D4_ + lane] = tot;
        if (lane == 0) {
            int c = 0;
            #pragma unroll
            for (int j = 0; j < 8; ++j) c += s_cnt[j];
            pcnt[bid] = c;
        }
    }
}

// ---------------------------------------------------------------
// Kernel 2 (512 blocks x 1024): block (nk, h) computes a HALF-dot over
// 64 of the 128 tokens of knowledge sentence nk=(n,k). The two halves
// combine via atomicAdd (2 commutative adds -> bitwise deterministic);
// the second-done block finalizes: scale, write ck_attn, argmax key.
// Masked nk: h==0 emits NEGINF directly, zero gather. With ~50% mask
// rate, ~256 active gather blocks spread across all 256 CUs.
__global__ __launch_bounds__(1024) void know_kernel(
        const int* __restrict__ know_tokens,
        const int* __restrict__ ck_mask,
        const float* __restrict__ emb,
        const float4* __restrict__ partial,
        const int* __restrict__ pcnt,
        float* __restrict__ ck_attn,
        float* __restrict__ pdot,
        int* __restrict__ kcnt,
        unsigned int* __restrict__ kdone,
        unsigned long long* __restrict__ key) {
    const int bid = blockIdx.x;
    const int nk = bid >> 1, h = bid & 1;
    const int n = nk >> 5, k = nk & 31;
    const int tid = threadIdx.x;
    const int tg = tid >> 7, lane = tid & 127;
    const float4* emb4 = (const float4*)emb;

    const int msk = ck_mask[nk];           // block-uniform

    if (msk == 0) {
        if (h == 0 && tid == 0) {
            const float v = NEGINF_;
            ck_attn[nk] = v;
            unsigned ub = __float_as_uint(v);
            ub = (ub & 0x80000000u) ? ~ub : (ub | 0x80000000u);
            const unsigned long long pk =
                ((unsigned long long)ub << 32) | (unsigned)(K_ - 1 - k);
            atomicMax(&key[n], pk);
        }
        return;
    }

    __shared__ float4 s_ctx[D4_];    // 2 KB
    __shared__ int s_tok[64];
    __shared__ float s_part[16];
    __shared__ int s_bcnt;

    if (tid < D4_) {
        // combine the 8 ctx partials -> scaled ctx_use slice
        float4 c = partial[(n * QPC_ + 0) * D4_ + tid];
        int cc = pcnt[n * QPC_ + 0];
        #pragma unroll
        for (int qq = 1; qq < QPC_; ++qq) {
            const float4 v = partial[(n * QPC_ + qq) * D4_ + tid];
            c.x += v.x; c.y += v.y; c.z += v.z; c.w += v.w;
            cc += pcnt[n * QPC_ + qq];
        }
        const float sc = INV_SQRT_D_ / sqrtf((float)cc);
        c.x *= sc; c.y *= sc; c.z *= sc; c.w *= sc;
        s_ctx[tid] = c;
    }
    if (tid < 64) {                        // exactly one wave: ballot is full
        const int tok = know_tokens[(size_t)nk * TK_ + h * 64 + tid];
        s_tok[tid] = tok;
        const unsigned long long b = __ballot(tok != 0);
        if (tid == 0) s_bcnt = (int)__popcll(b);
    }
    __syncthreads();

    const float4 c = s_ctx[lane];
    float acc = 0.f;
    #pragma unroll
    for (int i = 0; i < 8; ++i) {          // 8 tokens per thread-group pass
        const int tok = s_tok[tg + i * 8];
        const float4 v = emb4[(size_t)tok * D4_ + lane];  // unconditional
        const float d = v.x * c.x + v.y * c.y + v.z * c.z + v.w * c.w;
        acc += (tok != 0) ? d : 0.f;       // cndmask, no branch
    }
    #pragma unroll
    for (int off = 32; off > 0; off >>= 1) acc += __shfl_down(acc, off, 64);
    if ((tid & 63) == 0) s_part[tid >> 6] = acc;
    __syncthreads();

    if (tid == 0) {
        float half = 0.f;
        #pragma unroll
        for (int j = 0; j < 16; ++j) half += s_part[j];
        atomicAdd(&pdot[nk], half);        // 2 adds total: commutative, exact
        atomicAdd(&kcnt[nk], s_bcnt);
        __threadfence();
        const unsigned old = atomicAdd(&kdone[nk], 1u);
        if (old == 1u) {                   // second (last) half finalizes
            __threadfence();
            const float tot  = atomicAdd(&pdot[nk], 0.f);   // atomic read
            const int   cnt  = atomicAdd(&kcnt[nk], 0);
            const float v = tot * (INV_SQRT_D_ / sqrtf((float)cnt));
            ck_attn[nk] = v;
            unsigned ub = __float_as_uint(v);
            ub = (ub & 0x80000000u) ? ~ub : (ub | 0x80000000u);
            const unsigned long long pk =
                ((unsigned long long)ub << 32) | (unsigned)(K_ - 1 - k);
            atomicMax(&key[n], pk);
        }
    }
}

// ---------------------------------------------------------------
// Kernel 3 (1024 blocks x 128): chosen-knowledge rows only.
__global__ void gather_cs_kernel(const int* __restrict__ know_tokens,
                                 const int* __restrict__ cs_ids,
                                 const int* __restrict__ use_cs_ids,
                                 const unsigned long long* __restrict__ key,
                                 const float* __restrict__ emb,
                                 float* __restrict__ full_enc,
                                 float* __restrict__ full_mask) {
    const int bid = blockIdx.x;
    const int n = bid >> 7;
    const int r = bid & 127;
    const int tid = threadIdx.x;

    const int kbest = (K_ - 1) - (int)(key[n] & 0xffffffffull);
    const int ch = (use_cs_ids[0] != 0) ? cs_ids[n] : kbest;

    const int token = know_tokens[((size_t)n * K_ + ch) * TK_ + r];
    ((float4*)(full_enc + ((size_t)n * TOUT_ + r) * D_))[tid] =
        ((const float4*)(emb + (size_t)token * D_))[tid];
    if (tid == 0) full_mask[n * TOUT_ + r] = (token != 0) ? 1.0f : 0.0f;
}

// ---------------------------------------------------------------
extern "C" void kernel_launch(void* const* d_in, const int* in_sizes, int n_in,
                              void* d_out, int out_size, void* d_ws, size_t ws_size,
                              hipStream_t stream) {
    const int*   src_tokens  = (const int*)d_in[0];   // [N,Tc]
    const int*   know_tokens = (const int*)d_in[1];   // [N,K,Tk]
    const int*   ck_mask     = (const int*)d_in[2];   // [N,K] 0/1
    const int*   cs_ids      = (const int*)d_in[3];   // [N]
    const int*   use_cs_ids  = (const int*)d_in[4];   // scalar
    const float* emb         = (const float*)d_in[5]; // [V,D]

    float* out = (float*)d_out;
    float* full_enc  = out;
    float* full_mask = out + OUT_MASK_OFF_;
    float* ck_attn   = out + OUT_ATTN_OFF_;

    // workspace layout
    char* ws = (char*)d_ws;
    unsigned long long* key = (unsigned long long*)ws;        // 64 B
    float* pdot        = (float*)(ws + 64);                   // 1 KB
    int*   kcnt        = (int*)(ws + 64 + 1024);              // 1 KB
    unsigned int* kdone = (unsigned int*)(ws + 64 + 2048);    // 1 KB
    int*   pcnt        = (int*)(ws + 64 + 3072);              // 256 B
    float4* partial    = (float4*)(ws + 4096);                // 128 KB

    ctx_pool_kernel<<<POOLB_, 1024, 0, stream>>>(src_tokens, emb,
                                                 full_enc, full_mask,
                                                 partial, pcnt,
                                                 pdot, kcnt, kdone, key);
    know_kernel<<<KNOWB_ * 2, 1024, 0, stream>>>(know_tokens, ck_mask, emb,
                                                 partial, pcnt, ck_attn,
                                                 pdot, kcnt, kdone, key);
    gather_cs_kernel<<<N_ * TK_, 128, 0, stream>>>(know_tokens, cs_ids,
                                                   use_cs_ids, key, emb,
                                                   full_enc, full_mask);
}

// Round 14
// 19.783 us; speedup vs baseline: 1.5849x; 1.5849x over previous
//
#include <hip/hip_runtime.h>

// Problem constants (from reference setup_inputs)
#define N_  8
#define K_  32
#define TK_ 128
#define TC_ 256
#define D_  512
#define D4_ (D_ / 4)               // 128 float4 per emb row
#define TOUT_ (TK_ + TC_)          // 384
#define NEGINF_ (-1e20f)
#define INV_SQRT_D_ 0.044194173824159216f   // 1/sqrt(512)

// d_out layout (float): full_enc [N,384,512] | full_mask [N,384] | ck_attn [N,32]
#define OUT_MASK_OFF_ 1572864
#define OUT_ATTN_OFF_ 1575936

#define QPC_ 8                      // ctx slices per row
#define QTOK_ (TC_ / QPC_)          // 32 tokens per slice
#define POOLB_ (N_ * QPC_)          // 64 ctx pool blocks

// ---------------------------------------------------------------
// Kernel 1 (64 blocks x 1024): ctx pooling + write-through of the
// full_enc context rows (data already in registers). Block 0 resets key[].
__global__ __launch_bounds__(1024) void ctx_pool_kernel(
        const int* __restrict__ src_tokens,
        const float* __restrict__ emb,
        float* __restrict__ full_enc,
        float* __restrict__ full_mask,
        float4* __restrict__ partial,        // [64][128] float4
        int* __restrict__ pcnt,              // [64]
        unsigned long long* __restrict__ key) {
    const int bid = blockIdx.x;
    const int n = bid >> 3, q = bid & 7;
    const int tid = threadIdx.x;
    const int tg = tid >> 7, lane = tid & 127;
    const float4* emb4 = (const float4*)emb;

    __shared__ int s_tok[QTOK_];
    __shared__ float4 s_red[8][D4_];   // 16 KB
    __shared__ int s_cnt[8];

    if (bid == 0 && tid < N_) key[tid] = 0ull;   // per-call reset
    if (tid < QTOK_) s_tok[tid] = src_tokens[n * TC_ + q * QTOK_ + tid];
    __syncthreads();

    float4 acc = make_float4(0.f, 0.f, 0.f, 0.f);
    int cnt = 0;
    #pragma unroll
    for (int i = 0; i < QTOK_ / 8; ++i) {        // 4 tokens per thread
        const int t = tg + i * 8;
        const int tok = s_tok[t];
        const float4 v = emb4[(size_t)tok * D4_ + lane];  // row 0 is valid
        // write-through to full_enc context region (emb[tok] regardless of pad)
        const int row = TK_ + q * QTOK_ + t;
        ((float4*)(full_enc + ((size_t)n * TOUT_ + row) * D_))[lane] = v;
        if (lane == 0) full_mask[n * TOUT_ + row] = (tok != 0) ? 1.0f : 0.0f;

        const bool use = (tok != 0);
        cnt += use ? 1 : 0;
        acc.x += use ? v.x : 0.f;
        acc.y += use ? v.y : 0.f;
        acc.z += use ? v.z : 0.f;
        acc.w += use ? v.w : 0.f;
    }
    s_red[tg][lane] = acc;
    if (lane == 0) s_cnt[tg] = cnt;
    __syncthreads();

    if (tg == 0) {
        float4 tot = s_red[0][lane];
        #pragma unroll
        for (int j = 1; j < 8; ++j) {
            const float4 v = s_red[j][lane];
            tot.x += v.x; tot.y += v.y; tot.z += v.z; tot.w += v.w;
        }
        partial[bid * D4_ + lane] = tot;
        if (lane == 0) {
            int c = 0;
            #pragma unroll
            for (int j = 0; j < 8; ++j) c += s_cnt[j];
            pcnt[bid] = c;
        }
    }
}

// ---------------------------------------------------------------
// Kernel 2 (256 blocks x 512): block (n,k) = fused knowledge pool+dot
// with MASK-SKIP. 512-thread blocks -> 2 blocks/CU co-resident, so a
// masked block's instant exit leaves its CU busy with the paired block
// (expected busy-CU fraction ~75% vs 50% at 1024 thr).
__global__ __launch_bounds__(512) void know_kernel(
        const int* __restrict__ know_tokens,
        const int* __restrict__ ck_mask,
        const float* __restrict__ emb,
        const float4* __restrict__ partial,
        const int* __restrict__ pcnt,
        float* __restrict__ ck_attn,
        unsigned long long* __restrict__ key) {
    const int bid = blockIdx.x;
    const int tid = threadIdx.x;
    const int n = bid >> 5, k = bid & 31;
    const int tg = tid >> 7, lane = tid & 127;   // 4 token-groups x 128 lanes
    const float4* emb4 = (const float4*)emb;

    __shared__ float4 s_ctx[D4_];    // 2 KB
    __shared__ int s_tok[TK_];
    __shared__ float s_part[8];
    __shared__ int s_bcnt[2];

    const int msk = ck_mask[bid];    // block-uniform

    if (msk != 0) {
        if (tid < TK_) {
            // issue token loads FIRST (independent of partials)
            const int tok = know_tokens[(size_t)bid * TK_ + tid];
            s_tok[tid] = tok;
            const unsigned long long b = __ballot(tok != 0);  // waves 0,1 full
            if ((tid & 63) == 0) s_bcnt[tid >> 6] = (int)__popcll(b);
        }
        if (tid < D4_) {
            // combine the 8 ctx partials -> scaled ctx_use slice
            float4 c = partial[(n * QPC_ + 0) * D4_ + tid];
            int cc = pcnt[n * QPC_ + 0];
            #pragma unroll
            for (int qq = 1; qq < QPC_; ++qq) {
                const float4 v = partial[(n * QPC_ + qq) * D4_ + tid];
                c.x += v.x; c.y += v.y; c.z += v.z; c.w += v.w;
                cc += pcnt[n * QPC_ + qq];
            }
            const float sc = INV_SQRT_D_ / sqrtf((float)cc);
            c.x *= sc; c.y *= sc; c.z *= sc; c.w *= sc;
            s_ctx[tid] = c;
        }
        __syncthreads();

        const float4 c = s_ctx[lane];
        float acc = 0.f;
        #pragma unroll
        for (int i = 0; i < TK_ / 4; ++i) {      // 32 tokens per thread
            const int tok = s_tok[tg + i * 4];
            const float4 v = emb4[(size_t)tok * D4_ + lane];  // unconditional
            const float d = v.x * c.x + v.y * c.y + v.z * c.z + v.w * c.w;
            acc += (tok != 0) ? d : 0.f;         // cndmask, no branch
        }
        #pragma unroll
        for (int off = 32; off > 0; off >>= 1) acc += __shfl_down(acc, off, 64);
        if ((tid & 63) == 0) s_part[tid >> 6] = acc;
        __syncthreads();
    }

    if (tid == 0) {
        float v;
        if (msk != 0) {
            v = 0.f;
            #pragma unroll
            for (int j = 0; j < 8; ++j) v += s_part[j];
            const int cnt = s_bcnt[0] + s_bcnt[1];
            v *= INV_SQRT_D_ / sqrtf((float)cnt);
        } else {
            v = NEGINF_;                          // exact reference value
        }
        ck_attn[bid] = v;

        // order-preserving float encoding; ties -> smaller k (numpy first-max)
        unsigned ub = __float_as_uint(v);
        ub = (ub & 0x80000000u) ? ~ub : (ub | 0x80000000u);
        const unsigned long long pk =
            ((unsigned long long)ub << 32) | (unsigned)(K_ - 1 - k);
        atomicMax(&key[n], pk);
    }
}

// ---------------------------------------------------------------
// Kernel 3 (1024 blocks x 128): chosen-knowledge rows only.
__global__ void gather_cs_kernel(const int* __restrict__ know_tokens,
                                 const int* __restrict__ cs_ids,
                                 const int* __restrict__ use_cs_ids,
                                 const unsigned long long* __restrict__ key,
                                 const float* __restrict__ emb,
                                 float* __restrict__ full_enc,
                                 float* __restrict__ full_mask) {
    const int bid = blockIdx.x;
    const int n = bid >> 7;
    const int r = bid & 127;
    const int tid = threadIdx.x;

    const int kbest = (K_ - 1) - (int)(key[n] & 0xffffffffull);
    const int ch = (use_cs_ids[0] != 0) ? cs_ids[n] : kbest;

    const int token = know_tokens[((size_t)n * K_ + ch) * TK_ + r];
    ((float4*)(full_enc + ((size_t)n * TOUT_ + r) * D_))[tid] =
        ((const float4*)(emb + (size_t)token * D_))[tid];
    if (tid == 0) full_mask[n * TOUT_ + r] = (token != 0) ? 1.0f : 0.0f;
}

// ---------------------------------------------------------------
extern "C" void kernel_launch(void* const* d_in, const int* in_sizes, int n_in,
                              void* d_out, int out_size, void* d_ws, size_t ws_size,
                              hipStream_t stream) {
    const int*   src_tokens  = (const int*)d_in[0];   // [N,Tc]
    const int*   know_tokens = (const int*)d_in[1];   // [N,K,Tk]
    const int*   ck_mask     = (const int*)d_in[2];   // [N,K] 0/1
    const int*   cs_ids      = (const int*)d_in[3];   // [N]
    const int*   use_cs_ids  = (const int*)d_in[4];   // scalar
    const float* emb         = (const float*)d_in[5]; // [V,D]

    float* out = (float*)d_out;
    float* full_enc  = out;
    float* full_mask = out + OUT_MASK_OFF_;
    float* ck_attn   = out + OUT_ATTN_OFF_;

    // workspace: key[8] ULL | pcnt[64] int | partial[64*128] float4
    char* ws = (char*)d_ws;
    unsigned long long* key = (unsigned long long*)ws;      // 64 B
    int* pcnt       = (int*)(ws + 64);                      // 256 B
    float4* partial = (float4*)(ws + 512);                  // 128 KB

    ctx_pool_kernel<<<POOLB_, 1024, 0, stream>>>(src_tokens, emb,
                                                 full_enc, full_mask,
                                                 partial, pcnt, key);
    know_kernel<<<N_ * K_, 512, 0, stream>>>(know_tokens, ck_mask, emb,
                                             partial, pcnt, ck_attn, key);
    gather_cs_kernel<<<N_ * TK_, 128, 0, stream>>>(know_tokens, cs_ids,
                                                   use_cs_ids, key, emb,
                                                   full_enc, full_mask);
}